// Round 14
// baseline (139.205 us; speedup 1.0000x reference)
//
#include <hip/hip_runtime.h>
#include <hip/hip_fp16.h>

#define D 128
#define LN_EPS 1e-5f

// Dtypes (R0-R7 forensics): x,W,b,gamma,beta fp32; edge_index int32; out fp32.
// Ladder: R8 234 | R12 154.4 | R17 152.4 | R18 281 REGRESS (global far-atomics)
// | R19 153.5 (~26us/dispatch overhead) | R20 203.8 REGRESS (same-CU DS-pipe)
// | R21 142.4 | R22 246 REGRESS (mega@256) | R23 140.6 | R24 hang | R25 mega
// true cost 363us (MEGA CLOSED) | R26 153.7 REGRESS (deferred GEMM hits P1)
// | R27 129.9 (fused_agg v2: scalar s_load csr pairs) | R28 183.9 REGRESS
// (lane=chunk P1 broke across-lane coalescing) | R29 130.2 (repro) |
// R30 127.4 BEST (flagbar(2) eliminated: every block computes all C bases
// from blocksum after bar1; zero cross-block sync past bar1).
// R31 = R30 + GEMM W-staging ELIMINATED: GEMM blocks read fp32 W directly
// from global (two float2 loads/k, 1KB working set/iter -> L1-streamed;
// GEMM blocks share no CU with build so L1/VALU are free). Removes the
// t=0 12MB L2 staging burst (192 blocks x 64KB) that collided with build
// P0's edge-read burst, plus the conversion pass + staging syncthreads.
// GEMM slack >> any L1-thrash slowdown (must finish only by p1flag ~35us).

static __device__ __forceinline__ float h2f(unsigned short h) {
    return __half2float(__builtin_bit_cast(__half, h));
}
static __device__ __forceinline__ unsigned short f2h(float f) {
    return __builtin_bit_cast(unsigned short, __float2half_rn(f));
}

// exact-match flag barrier among the C build blocks: phase p has its OWN
// 64-slot array (no reuse -> no overwrite hazard). ws poison != val; bounded.
static __device__ __forceinline__ void flagbar(int* slots, int c, int C, int phase) {
    __syncthreads();
    int val = 0x5A5A0001 + phase;
    int tid = threadIdx.x;
    if (tid == 0)
        __hip_atomic_store(&slots[phase * 64 + c], val, __ATOMIC_RELEASE, __HIP_MEMORY_SCOPE_AGENT);
    if (tid < C) {
        int guard = 1 << 19;   // bounded: miscalc -> visible fail, never hang
        while (--guard > 0 &&
               __hip_atomic_load(&slots[phase * 64 + tid], __ATOMIC_ACQUIRE, __HIP_MEMORY_SCOPE_AGENT) != val)
            __builtin_amdgcn_s_sleep(1);
    }
    __syncthreads();
}

#define P1DONE 0x5A5A00B1
#define GMAXR 8   // rows per wave in a GEMM block

// ---- build+concurrent-gemm: blocks <C build CSR; blocks >=C GEMM X@W
// immediately (overlaps P0), quiet-wait p1flag, scale by dinv, store Hh. ----
__global__ __launch_bounds__(1024) void build_gemm_kernel(
        const int* __restrict__ src, const int* __restrict__ dst,
        const float* __restrict__ x, const float* __restrict__ W,
        unsigned int* __restrict__ Hh,
        unsigned short* __restrict__ ghist, int* __restrict__ blocksum,
        int* __restrict__ rowptr, int* __restrict__ rowptr_loc,
        float* __restrict__ dinv,
        unsigned short* __restrict__ csr, int* __restrict__ bar,
        int* __restrict__ p1flag,
        int N, int E, int Ec, int C, int G) {
    extern __shared__ int lds[];           // max(N*4, 32KB)
    __shared__ int s_scan[20];
    __shared__ int s_base[65];             // exclusive bases for all C blocks + total
    int c = blockIdx.x;
    int tid = threadIdx.x;
    int lane = tid & 63, wv = tid >> 6;

    if (c >= C) {
        // -------- GEMM block (idle-CU work; fp32 W direct, no staging) -----
        const float2* Wv = (const float2*)W;   // row-major [128][128] fp32
        int gb = c - C;
        int nb = G - C;
        int nper = (N + nb - 1) / nb;
        int r0 = gb * nper;
        int rn = min(nper, N - r0); if (rn < 0) rn = 0;

        float2 acc[GMAXR];
        #pragma unroll
        for (int j = 0; j < GMAXR; j++) {
            acc[j] = make_float2(0.f, 0.f);
            int lr = wv + 16 * j;
            if (lr < rn) {
                float2 xr = ((const float2*)x)[(size_t)(r0 + lr) * 64 + lane];
                float y0 = 0.f, y1 = 0.f;
                #pragma unroll 8
                for (int k = 0; k < 64; k++) {
                    float g0 = __shfl(xr.x, k);
                    float g1 = __shfl(xr.y, k);
                    float2 wa = Wv[(2 * k) * 64 + lane];        // W[2k][c0], W[2k][c0+1]
                    float2 wb = Wv[(2 * k + 1) * 64 + lane];    // W[2k+1][c0], W[2k+1][c0+1]
                    y0 += g0 * wa.x + g1 * wb.x;
                    y1 += g0 * wa.y + g1 * wb.y;
                }
                acc[j] = make_float2(y0, y1);
            }
        }
        // quiet wait: ONE lane polls ONE word, coarse sleep (no traffic storm)
        if (tid == 0) {
            int guard = 1 << 15;
            while (--guard > 0 &&
                   __hip_atomic_load(p1flag, __ATOMIC_ACQUIRE, __HIP_MEMORY_SCOPE_AGENT) != P1DONE)
                __builtin_amdgcn_s_sleep(32);
        }
        __syncthreads();
        #pragma unroll
        for (int j = 0; j < GMAXR; j++) {
            int lr = wv + 16 * j;
            if (lr < rn) {
                float dr = dinv[r0 + lr];
                Hh[(size_t)(r0 + lr) * 64 + lane] =
                    (unsigned int)f2h(acc[j].x * dr) | ((unsigned int)f2h(acc[j].y * dr) << 16);
            }
        }
        return;
    }

    // ---------------- build block ----------------
    // P0: zero hist; histogram my chunk (LDS atomics)
    for (int i = tid; i < N; i += 1024) lds[i] = 0;
    __syncthreads();
    int lo = c * Ec, hi = min(lo + Ec, E);
    #pragma unroll 4
    for (int i = lo + tid; i < hi; i += 1024)
        atomicAdd(&lds[dst[i]], 1);
    __syncthreads();
    for (int i = tid; i < N; i += 1024)
        ghist[(size_t)c * N + i] = (unsigned short)lds[i];
    flagbar(bar, c, C, 0);

    // P1: per-node chunk-exclusive (in place, u16) -> deg/dinv; local scan.
    // NOTE (R28 lesson): this serial chain is COALESCED ACROSS LANES (2 lines
    // per wave-step, independent prefetchable addresses) — do not parallelize
    // it along the chunk axis.
    int nper = (N + C - 1) / C;
    int n0 = c * nper;
    int nn = min(nper, N - n0); if (nn < 0) nn = 0;
    int mydeg = 0;
    if (tid < nn) {
        int n = n0 + tid;
        int run = 0;
        #pragma unroll 8
        for (int cc = 0; cc < C; cc++) {
            int t = ghist[(size_t)cc * N + n];
            ghist[(size_t)cc * N + n] = (unsigned short)run;
            run += t;
        }
        mydeg = run;
        dinv[n] = rsqrtf((float)(run + 1));   // +1 self-loop
    }
    int incl = mydeg;
    #pragma unroll
    for (int off = 1; off < 64; off <<= 1) {
        int y = __shfl_up(incl, off);
        if (lane >= off) incl += y;
    }
    if (lane == 63) s_scan[wv] = incl;
    __syncthreads();
    if (tid == 0) {
        int run = 0;
        #pragma unroll
        for (int k = 0; k < 16; k++) { int t = s_scan[k]; s_scan[k] = run; run += t; }
        blocksum[c] = run;
    }
    __syncthreads();
    int lp = 0;
    if (tid < nn) {
        lp = s_scan[wv] + incl - mydeg;       // local (pre-base) prefix
        rowptr_loc[n0 + tid] = lp;            // cross-block readable after bar1
    }
    flagbar(bar, c, C, 1);
    if (c == 0 && tid == 0)
        __hip_atomic_store(p1flag, P1DONE, __ATOMIC_RELEASE, __HIP_MEMORY_SCOPE_AGENT);

    // P2': EVERY block computes ALL C bases itself (blocksum complete at bar1)
    // -> no third barrier needed.
    if (tid < 64) {
        int bs = (tid < C) ? blocksum[tid] : 0;
        int inc2 = bs;
        #pragma unroll
        for (int off = 1; off < 64; off <<= 1) {
            int y = __shfl_up(inc2, off);
            if (tid >= off) inc2 += y;
        }
        s_base[tid] = inc2 - bs;              // exclusive base of block tid
        if (tid == C - 1) s_base[64] = inc2;  // grand total
    }
    __syncthreads();
    // final rowptr for MY chunk (consumed only by fused_agg, next dispatch)
    if (tid < nn) rowptr[n0 + tid] = lp + s_base[c];
    if (c == C - 1 && tid == 0) rowptr[N] = s_base[64];

    // P3: cursors from rowptr_loc + per-block base + own chunk's ghist;
    // zero cross-block dependencies past bar1. 2B u16 stores, no glb atomics.
    for (int i = tid; i < N; i += 1024)
        lds[i] = rowptr_loc[i] + s_base[(unsigned)i / (unsigned)nper]
               + ghist[(size_t)c * N + i];
    __syncthreads();
    #pragma unroll 4
    for (int i = lo + tid; i < hi; i += 1024) {
        int d = dst[i];
        int pos = atomicAdd(&lds[d], 1);
        csr[pos] = (unsigned short)src[i];
    }
}

// ---- fused_agg v2 (R27-exact, proven): 1 wave/node, SGPR-uniform csr reads
// (s_load pairs), zero shfls, 2 independent gathers/pair, unroll 4. ----
__global__ __launch_bounds__(512) void fused_agg(const unsigned int* __restrict__ Hh,
                                                 const int* __restrict__ rowptr,
                                                 const unsigned short* __restrict__ csr,
                                                 const float* __restrict__ dinv,
                                                 const float* __restrict__ bias,
                                                 const float* __restrict__ gamma,
                                                 const float* __restrict__ beta,
                                                 float* __restrict__ out, int N) {
    int w = threadIdx.x >> 6, lane = threadIdx.x & 63;
    int node = blockIdx.x * 8 + w;
    if (node >= N) return;
    float dn = dinv[node];

    unsigned int hv0 = Hh[(size_t)node * 64 + lane];   // scaled: dinv[n]*H[n]
    float a0 = h2f((unsigned short)hv0);
    float a1 = h2f((unsigned short)(hv0 >> 16));

    // rowptr is wave-uniform; force it into SGPRs so csr reads scalarize.
    int start = __builtin_amdgcn_readfirstlane(rowptr[node]);
    int end   = __builtin_amdgcn_readfirstlane(rowptr[node + 1]);

    int k = start;
    if ((k & 1) && k < end) {          // odd head -> align to u32
        int sk = csr[k];
        unsigned int hv = Hh[(size_t)sk * 64 + lane];
        a0 += h2f((unsigned short)hv);
        a1 += h2f((unsigned short)(hv >> 16));
        k++;
    }
    int npair = (end - k) >> 1;
    const unsigned int* cp = (const unsigned int*)(csr + k);   // 4B-aligned
    #pragma unroll 4
    for (int j = 0; j < npair; j++) {
        unsigned int pr = cp[j];       // uniform SGPR addr -> s_load_dword
        int s0 = (int)(pr & 0xffffu);
        int s1 = (int)(pr >> 16);
        unsigned int hva = Hh[(size_t)s0 * 64 + lane];
        unsigned int hvb = Hh[(size_t)s1 * 64 + lane];
        a0 += h2f((unsigned short)hva);
        a1 += h2f((unsigned short)(hva >> 16));
        a0 += h2f((unsigned short)hvb);
        a1 += h2f((unsigned short)(hvb >> 16));
    }
    k += npair * 2;
    if (k < end) {                     // odd tail
        int sk = csr[k];
        unsigned int hv = Hh[(size_t)sk * 64 + lane];
        a0 += h2f((unsigned short)hv);
        a1 += h2f((unsigned short)(hv >> 16));
    }

    int c0 = lane * 2;
    float y0 = dn * a0 + bias[c0];
    float y1 = dn * a1 + bias[c0 + 1];

    float sum = y0 + y1, sq = y0 * y0 + y1 * y1;
    #pragma unroll
    for (int off = 32; off > 0; off >>= 1) {
        sum += __shfl_xor(sum, off);
        sq  += __shfl_xor(sq, off);
    }
    float mean = sum * (1.0f / D);
    float var  = sq * (1.0f / D) - mean * mean;
    float inv  = rsqrtf(var + LN_EPS);
    float o0 = (y0 - mean) * inv * gamma[c0] + beta[c0];
    float o1 = (y1 - mean) * inv * gamma[c0 + 1] + beta[c0 + 1];
    *(float2*)(out + (size_t)node * D + c0) = make_float2(o0, o1);
}

// ================= fallback (R8, proven): used only if ws too small =========

__global__ void deg_kernel(const int* __restrict__ dst, int* __restrict__ deg, int E) {
    int e = blockIdx.x * blockDim.x + threadIdx.x;
    if (e < E) atomicAdd(&deg[dst[e]], 1);
}
__global__ __launch_bounds__(1024) void scan_kernel(const int* __restrict__ deg,
                                                    int* __restrict__ rowptr,
                                                    int* __restrict__ fill,
                                                    float* __restrict__ dinv, int N) {
    __shared__ int s_wsum[16];
    __shared__ int s_woff[16];
    __shared__ int s_carry;
    int t = threadIdx.x;
    int lane = t & 63, w = t >> 6;
    if (t == 0) s_carry = 0;
    __syncthreads();
    for (int base = 0; base < N; base += 1024) {
        int i = base + t;
        int v = (i < N) ? deg[i] : 0;
        int incl = v;
        #pragma unroll
        for (int off = 1; off < 64; off <<= 1) {
            int y = __shfl_up(incl, off);
            if (lane >= off) incl += y;
        }
        if (lane == 63) s_wsum[w] = incl;
        __syncthreads();
        if (t == 0) {
            int run = s_carry;
            #pragma unroll
            for (int k = 0; k < 16; k++) { s_woff[k] = run; run += s_wsum[k]; }
            s_carry = run;
        }
        __syncthreads();
        if (i < N) {
            int rp = s_woff[w] + (incl - v);
            rowptr[i] = rp;
            fill[i] = rp;
            dinv[i] = rsqrtf((float)(v + 1));
        }
    }
    if (t == 0) rowptr[N] = s_carry;
}
__global__ void fill_kernel(const int* __restrict__ src, const int* __restrict__ dst,
                            int* __restrict__ fill, unsigned short* __restrict__ csr, int E) {
    int e = blockIdx.x * blockDim.x + threadIdx.x;
    if (e < E) {
        int pos = atomicAdd(&fill[dst[e]], 1);
        csr[pos] = (unsigned short)src[e];
    }
}
__global__ __launch_bounds__(512) void fused_fp32(const float* __restrict__ x,
                                                  const float* __restrict__ W,
                                                  const int* __restrict__ rowptr,
                                                  const unsigned short* __restrict__ csr,
                                                  const float* __restrict__ dinv,
                                                  const float* __restrict__ bias,
                                                  const float* __restrict__ gamma,
                                                  const float* __restrict__ beta,
                                                  float* __restrict__ out, int N) {
    __shared__ float sW[D * D];
    {
        const float4* Wv = (const float4*)W;
        float4* sWv = (float4*)sW;
        #pragma unroll
        for (int i = 0; i < (D * D / 4) / 512; i++)
            sWv[threadIdx.x + i * 512] = Wv[threadIdx.x + i * 512];
    }
    __syncthreads();
    int w = threadIdx.x >> 6, lane = threadIdx.x & 63;
    int node = blockIdx.x * 8 + w;
    if (node >= N) return;
    float dn = dinv[node];
    int c0 = lane * 2;
    float2 xv = *(const float2*)(x + (size_t)node * D + c0);
    float a0 = xv.x * dn * dn, a1 = xv.y * dn * dn;
    int start = rowptr[node], end = rowptr[node + 1];
    int base = start;
    for (; base + 64 <= end; base += 64) {
        int s = csr[base + lane];
        float wt = dinv[s] * dn;
        #pragma unroll 8
        for (int k = 0; k < 64; k++) {
            int sk = __shfl(s, k);
            float wk = __shfl(wt, k);
            float2 xs = *(const float2*)(x + (size_t)sk * D + c0);
            a0 += xs.x * wk; a1 += xs.y * wk;
        }
    }
    int rem = end - base;
    if (rem > 0) {
        int s = 0; float wt = 0.f;
        if (lane < rem) { s = csr[base + lane]; wt = dinv[s] * dn; }
        for (int k = 0; k < rem; k++) {
            int sk = __shfl(s, k);
            float wk = __shfl(wt, k);
            float2 xs = *(const float2*)(x + (size_t)sk * D + c0);
            a0 += xs.x * wk; a1 += xs.y * wk;
        }
    }
    float y0 = bias[c0], y1 = bias[c0 + 1];
    #pragma unroll 8
    for (int k = 0; k < 64; k++) {
        float g0 = __shfl(a0, k);
        float g1 = __shfl(a1, k);
        float2 w0 = *(const float2*)(sW + (2 * k) * D + c0);
        float2 w1 = *(const float2*)(sW + (2 * k + 1) * D + c0);
        y0 += g0 * w0.x + g1 * w1.x;
        y1 += g0 * w0.y + g1 * w1.y;
    }
    float sum = y0 + y1, sq = y0 * y0 + y1 * y1;
    #pragma unroll
    for (int off = 32; off > 0; off >>= 1) {
        sum += __shfl_xor(sum, off);
        sq  += __shfl_xor(sq, off);
    }
    float mean = sum * (1.0f / D);
    float var  = sq * (1.0f / D) - mean * mean;
    float inv  = rsqrtf(var + LN_EPS);
    float o0 = (y0 - mean) * inv * gamma[c0] + beta[c0];
    float o1 = (y1 - mean) * inv * gamma[c0 + 1] + beta[c0 + 1];
    *(float2*)(out + (size_t)node * D + c0) = make_float2(o0, o1);
}

extern "C" void kernel_launch(void* const* d_in, const int* in_sizes, int n_in,
                              void* d_out, int out_size, void* d_ws, size_t ws_size,
                              hipStream_t stream) {
    const float* x     = (const float*)d_in[0];
    const int*   ei    = (const int*)d_in[1];
    const float* W     = (const float*)d_in[2];
    const float* bias  = (const float*)d_in[3];
    const float* gamma = (const float*)d_in[4];
    const float* beta  = (const float*)d_in[5];
    float*       out   = (float*)d_out;

    int N = in_sizes[0] / D;
    int E = in_sizes[1] / 2;
    const int* src = ei;
    const int* dst = ei + E;

    char* ws = (char*)d_ws;
    size_t off = 0;
    auto carve = [&](size_t bytes) { size_t p = off; off = (off + bytes + 15) & ~15UL; return (void*)(ws + p); };
    int*            bar      = (int*)           carve(3 * 64 * 4);   // build flags
    int*            p1flag   = (int*)           carve(16);           // single flag
    int*            blocksum = (int*)           carve(64 * 4);
    int*            rowptr   = (int*)           carve((size_t)(N + 1) * 4);
    int*            rowptr_l = (int*)           carve((size_t)N * 4); // local prefixes
    float*          dinv     = (float*)         carve((size_t)N * 4);
    unsigned short* csr      = (unsigned short*)carve((size_t)E * 2);
    unsigned int*   Hh       = (unsigned int*)  carve((size_t)N * (D / 2) * 4);
    size_t fixed_end = off;

    // chunk count C = build-block count; each chunk needs N*2 B of u16 ghist.
    // C=64 is the measured optimum (build ~ a + 0.4*C us; C=256 doubled it).
    int C = 0;
    if (ws_size > fixed_end + 16) {
        size_t avail = ws_size - fixed_end - 16;
        size_t cmax = avail / ((size_t)N * 2);
        C = (int)((cmax > 64) ? 64 : cmax);
    }

    const int G = 256;   // full chip: C build blocks + (G-C) GEMM blocks
    // GEMM capacity: (G-C)*16*GMAXR rows; build P1/rowptr needs nper<=1024
    bool gemm_ok = (C >= 16) && ((size_t)(G - C) * 16 * GMAXR >= (size_t)N)
                   && ((N + C - 1) / C <= 1024);

    if (gemm_ok) {
        unsigned short* ghist = (unsigned short*)carve((size_t)C * N * 2);
        int Ec = (E + C - 1) / C;
        size_t lds = (size_t)N * 4;
        if (lds < (size_t)(D * D / 2) * 4) lds = (size_t)(D * D / 2) * 4;
        // 2 dispatches: build(2-barrier)+concurrent-gemm(no W staging)
        //               -> fused_agg v2
        build_gemm_kernel<<<G, 1024, lds, stream>>>(src, dst, x, W, Hh, ghist,
                                                    blocksum, rowptr, rowptr_l,
                                                    dinv, csr, bar, p1flag,
                                                    N, E, Ec, C, G);
        fused_agg<<<(N + 7) / 8, 512, 0, stream>>>(Hh, rowptr, csr, dinv,
                                                   bias, gamma, beta, out, N);
    } else {
        // fallback: proven R8 path
        int* deg  = (int*)carve((size_t)N * 4);
        int* fill = (int*)carve((size_t)N * 4);
        hipMemsetAsync(deg, 0, (size_t)N * 4, stream);
        deg_kernel<<<(E + 255) / 256, 256, 0, stream>>>(dst, deg, E);
        scan_kernel<<<1, 1024, 0, stream>>>(deg, rowptr, fill, dinv, N);
        fill_kernel<<<(E + 255) / 256, 256, 0, stream>>>(src, dst, fill, csr, E);
        fused_fp32<<<(N + 7) / 8, 512, 0, stream>>>(x, W, rowptr, csr, dinv,
                                                    bias, gamma, beta, out, N);
    }
}

// Round 15
// 126.495 us; speedup vs baseline: 1.1005x; 1.1005x over previous
//
#include <hip/hip_runtime.h>
#include <hip/hip_fp16.h>

#define D 128
#define LN_EPS 1e-5f

// Dtypes (R0-R7 forensics): x,W,b,gamma,beta fp32; edge_index int32; out fp32.
// Ladder: R8 234 | R12 154.4 | R17 152.4 | R18 281 REGRESS (global far-atomics)
// | R19 153.5 (~26us/dispatch overhead) | R20 203.8 REGRESS (same-CU DS-pipe)
// | R21 142.4 | R22 246 REGRESS (mega@256) | R23 140.6 | R24 hang | R25 mega
// true cost 363us (MEGA CLOSED) | R26 153.7 REGRESS (deferred GEMM hits P1)
// | R27 129.9 (fused_agg v2: scalar s_load csr pairs) | R28 183.9 REGRESS
// (lane=chunk P1 broke across-lane coalescing) | R29 130.2 (repro) |
// R30 127.4 BEST (flagbar(2) eliminated) | R31 139.2 REGRESS: W-direct GEMM
// reads 64KB W per WAVE (>32KB L1) -> 196MB L2 traffic vs 12MB staged-once;
// LDS fp16 W staging is load-bearing. Build's ~7us concurrency stretch is
// steady-state L2/HBM sharing (deferral R26 and removal R31 both worse).
// R32 = R30 byte-exact revert. All mechanisms probed; R30 = all wins.

static __device__ __forceinline__ float h2f(unsigned short h) {
    return __half2float(__builtin_bit_cast(__half, h));
}
static __device__ __forceinline__ unsigned short f2h(float f) {
    return __builtin_bit_cast(unsigned short, __float2half_rn(f));
}

// exact-match flag barrier among the C build blocks: phase p has its OWN
// 64-slot array (no reuse -> no overwrite hazard). ws poison != val; bounded.
static __device__ __forceinline__ void flagbar(int* slots, int c, int C, int phase) {
    __syncthreads();
    int val = 0x5A5A0001 + phase;
    int tid = threadIdx.x;
    if (tid == 0)
        __hip_atomic_store(&slots[phase * 64 + c], val, __ATOMIC_RELEASE, __HIP_MEMORY_SCOPE_AGENT);
    if (tid < C) {
        int guard = 1 << 19;   // bounded: miscalc -> visible fail, never hang
        while (--guard > 0 &&
               __hip_atomic_load(&slots[phase * 64 + tid], __ATOMIC_ACQUIRE, __HIP_MEMORY_SCOPE_AGENT) != val)
            __builtin_amdgcn_s_sleep(1);
    }
    __syncthreads();
}

#define P1DONE 0x5A5A00B1
#define GMAXR 8   // rows per wave in a GEMM block

// ---- build+concurrent-gemm: blocks <C build CSR; blocks >=C GEMM X@W
// immediately (overlaps P0), quiet-wait p1flag, scale by dinv, store Hh. ----
__global__ __launch_bounds__(1024) void build_gemm_kernel(
        const int* __restrict__ src, const int* __restrict__ dst,
        const float* __restrict__ x, const float* __restrict__ W,
        unsigned int* __restrict__ Hh,
        unsigned short* __restrict__ ghist, int* __restrict__ blocksum,
        int* __restrict__ rowptr, int* __restrict__ rowptr_loc,
        float* __restrict__ dinv,
        unsigned short* __restrict__ csr, int* __restrict__ bar,
        int* __restrict__ p1flag,
        int N, int E, int Ec, int C, int G) {
    extern __shared__ int lds[];           // max(N*4, 32KB)
    __shared__ int s_scan[20];
    __shared__ int s_base[65];             // exclusive bases for all C blocks + total
    int c = blockIdx.x;
    int tid = threadIdx.x;
    int lane = tid & 63, wv = tid >> 6;

    if (c >= C) {
        // ---------------- GEMM block (idle-CU work) ----------------
        unsigned int* sWh = (unsigned int*)lds;    // 32 KB fp16-packed W (L1-fit)
        #pragma unroll
        for (int i = tid; i < D * D / 2; i += 1024) {
            float2 v = ((const float2*)W)[i];
            sWh[i] = (unsigned int)f2h(v.x) | ((unsigned int)f2h(v.y) << 16);
        }
        __syncthreads();
        int gb = c - C;
        int nb = G - C;
        int nper = (N + nb - 1) / nb;
        int r0 = gb * nper;
        int rn = min(nper, N - r0); if (rn < 0) rn = 0;

        float2 acc[GMAXR];
        #pragma unroll
        for (int j = 0; j < GMAXR; j++) {
            acc[j] = make_float2(0.f, 0.f);
            int lr = wv + 16 * j;
            if (lr < rn) {
                float2 xr = ((const float2*)x)[(size_t)(r0 + lr) * 64 + lane];
                float y0 = 0.f, y1 = 0.f;
                #pragma unroll 8
                for (int k = 0; k < 64; k++) {
                    float g0 = __shfl(xr.x, k);
                    float g1 = __shfl(xr.y, k);
                    unsigned int w0 = sWh[(2 * k) * 64 + lane];
                    unsigned int w1 = sWh[(2 * k + 1) * 64 + lane];
                    y0 += g0 * h2f((unsigned short)w0) + g1 * h2f((unsigned short)w1);
                    y1 += g0 * h2f((unsigned short)(w0 >> 16)) + g1 * h2f((unsigned short)(w1 >> 16));
                }
                acc[j] = make_float2(y0, y1);
            }
        }
        // quiet wait: ONE lane polls ONE word, coarse sleep (no traffic storm)
        if (tid == 0) {
            int guard = 1 << 15;
            while (--guard > 0 &&
                   __hip_atomic_load(p1flag, __ATOMIC_ACQUIRE, __HIP_MEMORY_SCOPE_AGENT) != P1DONE)
                __builtin_amdgcn_s_sleep(32);
        }
        __syncthreads();
        #pragma unroll
        for (int j = 0; j < GMAXR; j++) {
            int lr = wv + 16 * j;
            if (lr < rn) {
                float dr = dinv[r0 + lr];
                Hh[(size_t)(r0 + lr) * 64 + lane] =
                    (unsigned int)f2h(acc[j].x * dr) | ((unsigned int)f2h(acc[j].y * dr) << 16);
            }
        }
        return;
    }

    // ---------------- build block ----------------
    // P0: zero hist; histogram my chunk (LDS atomics)
    for (int i = tid; i < N; i += 1024) lds[i] = 0;
    __syncthreads();
    int lo = c * Ec, hi = min(lo + Ec, E);
    #pragma unroll 4
    for (int i = lo + tid; i < hi; i += 1024)
        atomicAdd(&lds[dst[i]], 1);
    __syncthreads();
    for (int i = tid; i < N; i += 1024)
        ghist[(size_t)c * N + i] = (unsigned short)lds[i];
    flagbar(bar, c, C, 0);

    // P1: per-node chunk-exclusive (in place, u16) -> deg/dinv; local scan.
    // NOTE (R28 lesson): this serial chain is COALESCED ACROSS LANES (2 lines
    // per wave-step, independent prefetchable addresses) — do not parallelize
    // it along the chunk axis.
    int nper = (N + C - 1) / C;
    int n0 = c * nper;
    int nn = min(nper, N - n0); if (nn < 0) nn = 0;
    int mydeg = 0;
    if (tid < nn) {
        int n = n0 + tid;
        int run = 0;
        #pragma unroll 8
        for (int cc = 0; cc < C; cc++) {
            int t = ghist[(size_t)cc * N + n];
            ghist[(size_t)cc * N + n] = (unsigned short)run;
            run += t;
        }
        mydeg = run;
        dinv[n] = rsqrtf((float)(run + 1));   // +1 self-loop
    }
    int incl = mydeg;
    #pragma unroll
    for (int off = 1; off < 64; off <<= 1) {
        int y = __shfl_up(incl, off);
        if (lane >= off) incl += y;
    }
    if (lane == 63) s_scan[wv] = incl;
    __syncthreads();
    if (tid == 0) {
        int run = 0;
        #pragma unroll
        for (int k = 0; k < 16; k++) { int t = s_scan[k]; s_scan[k] = run; run += t; }
        blocksum[c] = run;
    }
    __syncthreads();
    int lp = 0;
    if (tid < nn) {
        lp = s_scan[wv] + incl - mydeg;       // local (pre-base) prefix
        rowptr_loc[n0 + tid] = lp;            // cross-block readable after bar1
    }
    flagbar(bar, c, C, 1);
    if (c == 0 && tid == 0)
        __hip_atomic_store(p1flag, P1DONE, __ATOMIC_RELEASE, __HIP_MEMORY_SCOPE_AGENT);

    // P2': EVERY block computes ALL C bases itself (blocksum complete at bar1)
    // -> no third barrier needed.
    if (tid < 64) {
        int bs = (tid < C) ? blocksum[tid] : 0;
        int inc2 = bs;
        #pragma unroll
        for (int off = 1; off < 64; off <<= 1) {
            int y = __shfl_up(inc2, off);
            if (tid >= off) inc2 += y;
        }
        s_base[tid] = inc2 - bs;              // exclusive base of block tid
        if (tid == C - 1) s_base[64] = inc2;  // grand total
    }
    __syncthreads();
    // final rowptr for MY chunk (consumed only by fused_agg, next dispatch)
    if (tid < nn) rowptr[n0 + tid] = lp + s_base[c];
    if (c == C - 1 && tid == 0) rowptr[N] = s_base[64];

    // P3: cursors from rowptr_loc + per-block base + own chunk's ghist;
    // zero cross-block dependencies past bar1. 2B u16 stores, no glb atomics.
    for (int i = tid; i < N; i += 1024)
        lds[i] = rowptr_loc[i] + s_base[(unsigned)i / (unsigned)nper]
               + ghist[(size_t)c * N + i];
    __syncthreads();
    #pragma unroll 4
    for (int i = lo + tid; i < hi; i += 1024) {
        int d = dst[i];
        int pos = atomicAdd(&lds[d], 1);
        csr[pos] = (unsigned short)src[i];
    }
}

// ---- fused_agg v2 (R27-exact, proven): 1 wave/node, SGPR-uniform csr reads
// (s_load pairs), zero shfls, 2 independent gathers/pair, unroll 4. ----
__global__ __launch_bounds__(512) void fused_agg(const unsigned int* __restrict__ Hh,
                                                 const int* __restrict__ rowptr,
                                                 const unsigned short* __restrict__ csr,
                                                 const float* __restrict__ dinv,
                                                 const float* __restrict__ bias,
                                                 const float* __restrict__ gamma,
                                                 const float* __restrict__ beta,
                                                 float* __restrict__ out, int N) {
    int w = threadIdx.x >> 6, lane = threadIdx.x & 63;
    int node = blockIdx.x * 8 + w;
    if (node >= N) return;
    float dn = dinv[node];

    unsigned int hv0 = Hh[(size_t)node * 64 + lane];   // scaled: dinv[n]*H[n]
    float a0 = h2f((unsigned short)hv0);
    float a1 = h2f((unsigned short)(hv0 >> 16));

    // rowptr is wave-uniform; force it into SGPRs so csr reads scalarize.
    int start = __builtin_amdgcn_readfirstlane(rowptr[node]);
    int end   = __builtin_amdgcn_readfirstlane(rowptr[node + 1]);

    int k = start;
    if ((k & 1) && k < end) {          // odd head -> align to u32
        int sk = csr[k];
        unsigned int hv = Hh[(size_t)sk * 64 + lane];
        a0 += h2f((unsigned short)hv);
        a1 += h2f((unsigned short)(hv >> 16));
        k++;
    }
    int npair = (end - k) >> 1;
    const unsigned int* cp = (const unsigned int*)(csr + k);   // 4B-aligned
    #pragma unroll 4
    for (int j = 0; j < npair; j++) {
        unsigned int pr = cp[j];       // uniform SGPR addr -> s_load_dword
        int s0 = (int)(pr & 0xffffu);
        int s1 = (int)(pr >> 16);
        unsigned int hva = Hh[(size_t)s0 * 64 + lane];
        unsigned int hvb = Hh[(size_t)s1 * 64 + lane];
        a0 += h2f((unsigned short)hva);
        a1 += h2f((unsigned short)(hva >> 16));
        a0 += h2f((unsigned short)hvb);
        a1 += h2f((unsigned short)(hvb >> 16));
    }
    k += npair * 2;
    if (k < end) {                     // odd tail
        int sk = csr[k];
        unsigned int hv = Hh[(size_t)sk * 64 + lane];
        a0 += h2f((unsigned short)hv);
        a1 += h2f((unsigned short)(hv >> 16));
    }

    int c0 = lane * 2;
    float y0 = dn * a0 + bias[c0];
    float y1 = dn * a1 + bias[c0 + 1];

    float sum = y0 + y1, sq = y0 * y0 + y1 * y1;
    #pragma unroll
    for (int off = 32; off > 0; off >>= 1) {
        sum += __shfl_xor(sum, off);
        sq  += __shfl_xor(sq, off);
    }
    float mean = sum * (1.0f / D);
    float var  = sq * (1.0f / D) - mean * mean;
    float inv  = rsqrtf(var + LN_EPS);
    float o0 = (y0 - mean) * inv * gamma[c0] + beta[c0];
    float o1 = (y1 - mean) * inv * gamma[c0 + 1] + beta[c0 + 1];
    *(float2*)(out + (size_t)node * D + c0) = make_float2(o0, o1);
}

// ================= fallback (R8, proven): used only if ws too small =========

__global__ void deg_kernel(const int* __restrict__ dst, int* __restrict__ deg, int E) {
    int e = blockIdx.x * blockDim.x + threadIdx.x;
    if (e < E) atomicAdd(&deg[dst[e]], 1);
}
__global__ __launch_bounds__(1024) void scan_kernel(const int* __restrict__ deg,
                                                    int* __restrict__ rowptr,
                                                    int* __restrict__ fill,
                                                    float* __restrict__ dinv, int N) {
    __shared__ int s_wsum[16];
    __shared__ int s_woff[16];
    __shared__ int s_carry;
    int t = threadIdx.x;
    int lane = t & 63, w = t >> 6;
    if (t == 0) s_carry = 0;
    __syncthreads();
    for (int base = 0; base < N; base += 1024) {
        int i = base + t;
        int v = (i < N) ? deg[i] : 0;
        int incl = v;
        #pragma unroll
        for (int off = 1; off < 64; off <<= 1) {
            int y = __shfl_up(incl, off);
            if (lane >= off) incl += y;
        }
        if (lane == 63) s_wsum[w] = incl;
        __syncthreads();
        if (t == 0) {
            int run = s_carry;
            #pragma unroll
            for (int k = 0; k < 16; k++) { s_woff[k] = run; run += s_wsum[k]; }
            s_carry = run;
        }
        __syncthreads();
        if (i < N) {
            int rp = s_woff[w] + (incl - v);
            rowptr[i] = rp;
            fill[i] = rp;
            dinv[i] = rsqrtf((float)(v + 1));
        }
    }
    if (t == 0) rowptr[N] = s_carry;
}
__global__ void fill_kernel(const int* __restrict__ src, const int* __restrict__ dst,
                            int* __restrict__ fill, unsigned short* __restrict__ csr, int E) {
    int e = blockIdx.x * blockDim.x + threadIdx.x;
    if (e < E) {
        int pos = atomicAdd(&fill[dst[e]], 1);
        csr[pos] = (unsigned short)src[e];
    }
}
__global__ __launch_bounds__(512) void fused_fp32(const float* __restrict__ x,
                                                  const float* __restrict__ W,
                                                  const int* __restrict__ rowptr,
                                                  const unsigned short* __restrict__ csr,
                                                  const float* __restrict__ dinv,
                                                  const float* __restrict__ bias,
                                                  const float* __restrict__ gamma,
                                                  const float* __restrict__ beta,
                                                  float* __restrict__ out, int N) {
    __shared__ float sW[D * D];
    {
        const float4* Wv = (const float4*)W;
        float4* sWv = (float4*)sW;
        #pragma unroll
        for (int i = 0; i < (D * D / 4) / 512; i++)
            sWv[threadIdx.x + i * 512] = Wv[threadIdx.x + i * 512];
    }
    __syncthreads();
    int w = threadIdx.x >> 6, lane = threadIdx.x & 63;
    int node = blockIdx.x * 8 + w;
    if (node >= N) return;
    float dn = dinv[node];
    int c0 = lane * 2;
    float2 xv = *(const float2*)(x + (size_t)node * D + c0);
    float a0 = xv.x * dn * dn, a1 = xv.y * dn * dn;
    int start = rowptr[node], end = rowptr[node + 1];
    int base = start;
    for (; base + 64 <= end; base += 64) {
        int s = csr[base + lane];
        float wt = dinv[s] * dn;
        #pragma unroll 8
        for (int k = 0; k < 64; k++) {
            int sk = __shfl(s, k);
            float wk = __shfl(wt, k);
            float2 xs = *(const float2*)(x + (size_t)sk * D + c0);
            a0 += xs.x * wk; a1 += xs.y * wk;
        }
    }
    int rem = end - base;
    if (rem > 0) {
        int s = 0; float wt = 0.f;
        if (lane < rem) { s = csr[base + lane]; wt = dinv[s] * dn; }
        for (int k = 0; k < rem; k++) {
            int sk = __shfl(s, k);
            float wk = __shfl(wt, k);
            float2 xs = *(const float2*)(x + (size_t)sk * D + c0);
            a0 += xs.x * wk; a1 += xs.y * wk;
        }
    }
    float y0 = bias[c0], y1 = bias[c0 + 1];
    #pragma unroll 8
    for (int k = 0; k < 64; k++) {
        float g0 = __shfl(a0, k);
        float g1 = __shfl(a1, k);
        float2 w0 = *(const float2*)(sW + (2 * k) * D + c0);
        float2 w1 = *(const float2*)(sW + (2 * k + 1) * D + c0);
        y0 += g0 * w0.x + g1 * w1.x;
        y1 += g0 * w0.y + g1 * w1.y;
    }
    float sum = y0 + y1, sq = y0 * y0 + y1 * y1;
    #pragma unroll
    for (int off = 32; off > 0; off >>= 1) {
        sum += __shfl_xor(sum, off);
        sq  += __shfl_xor(sq, off);
    }
    float mean = sum * (1.0f / D);
    float var  = sq * (1.0f / D) - mean * mean;
    float inv  = rsqrtf(var + LN_EPS);
    float o0 = (y0 - mean) * inv * gamma[c0] + beta[c0];
    float o1 = (y1 - mean) * inv * gamma[c0 + 1] + beta[c0 + 1];
    *(float2*)(out + (size_t)node * D + c0) = make_float2(o0, o1);
}

extern "C" void kernel_launch(void* const* d_in, const int* in_sizes, int n_in,
                              void* d_out, int out_size, void* d_ws, size_t ws_size,
                              hipStream_t stream) {
    const float* x     = (const float*)d_in[0];
    const int*   ei    = (const int*)d_in[1];
    const float* W     = (const float*)d_in[2];
    const float* bias  = (const float*)d_in[3];
    const float* gamma = (const float*)d_in[4];
    const float* beta  = (const float*)d_in[5];
    float*       out   = (float*)d_out;

    int N = in_sizes[0] / D;
    int E = in_sizes[1] / 2;
    const int* src = ei;
    const int* dst = ei + E;

    char* ws = (char*)d_ws;
    size_t off = 0;
    auto carve = [&](size_t bytes) { size_t p = off; off = (off + bytes + 15) & ~15UL; return (void*)(ws + p); };
    int*            bar      = (int*)           carve(3 * 64 * 4);   // build flags
    int*            p1flag   = (int*)           carve(16);           // single flag
    int*            blocksum = (int*)           carve(64 * 4);
    int*            rowptr   = (int*)           carve((size_t)(N + 1) * 4);
    int*            rowptr_l = (int*)           carve((size_t)N * 4); // local prefixes
    float*          dinv     = (float*)         carve((size_t)N * 4);
    unsigned short* csr      = (unsigned short*)carve((size_t)E * 2);
    unsigned int*   Hh       = (unsigned int*)  carve((size_t)N * (D / 2) * 4);
    size_t fixed_end = off;

    // chunk count C = build-block count; each chunk needs N*2 B of u16 ghist.
    // C=64 is the measured optimum (build ~ a + 0.4*C us; C=256 doubled it).
    int C = 0;
    if (ws_size > fixed_end + 16) {
        size_t avail = ws_size - fixed_end - 16;
        size_t cmax = avail / ((size_t)N * 2);
        C = (int)((cmax > 64) ? 64 : cmax);
    }

    const int G = 256;   // full chip: C build blocks + (G-C) GEMM blocks
    // GEMM capacity: (G-C)*16*GMAXR rows; build P1/rowptr needs nper<=1024
    bool gemm_ok = (C >= 16) && ((size_t)(G - C) * 16 * GMAXR >= (size_t)N)
                   && ((N + C - 1) / C <= 1024);

    if (gemm_ok) {
        unsigned short* ghist = (unsigned short*)carve((size_t)C * N * 2);
        int Ec = (E + C - 1) / C;
        size_t lds = (size_t)N * 4;
        if (lds < (size_t)(D * D / 2) * 4) lds = (size_t)(D * D / 2) * 4;
        // 2 dispatches: build(2-barrier)+concurrent-gemm -> fused_agg v2
        build_gemm_kernel<<<G, 1024, lds, stream>>>(src, dst, x, W, Hh, ghist,
                                                    blocksum, rowptr, rowptr_l,
                                                    dinv, csr, bar, p1flag,
                                                    N, E, Ec, C, G);
        fused_agg<<<(N + 7) / 8, 512, 0, stream>>>(Hh, rowptr, csr, dinv,
                                                   bias, gamma, beta, out, N);
    } else {
        // fallback: proven R8 path
        int* deg  = (int*)carve((size_t)N * 4);
        int* fill = (int*)carve((size_t)N * 4);
        hipMemsetAsync(deg, 0, (size_t)N * 4, stream);
        deg_kernel<<<(E + 255) / 256, 256, 0, stream>>>(dst, deg, E);
        scan_kernel<<<1, 1024, 0, stream>>>(deg, rowptr, fill, dinv, N);
        fill_kernel<<<(E + 255) / 256, 256, 0, stream>>>(src, dst, fill, csr, E);
        fused_fp32<<<(N + 7) / 8, 512, 0, stream>>>(x, W, rowptr, csr, dinv,
                                                    bias, gamma, beta, out, N);
    }
}